// Round 1
// baseline (522.005 us; speedup 1.0000x reference)
//
#include <hip/hip_runtime.h>
#include <hip/hip_bf16.h>
#include <stdint.h>

// Problem dims (compile-time constants from the reference)
#define IN_F  2048
#define HID_F 8192
#define OUT_F 2048
#define BATCH 4096

typedef __attribute__((ext_vector_type(8))) short bf16x8;
typedef __attribute__((ext_vector_type(4))) float f32x4;

__device__ __forceinline__ unsigned short f32_to_bf16(float f) {
  union { float f; uint32_t u; } v; v.f = f;
  uint32_t u = v.u;
  uint32_t r = u + 0x7FFF + ((u >> 16) & 1);   // RNE
  return (unsigned short)(r >> 16);
}

__device__ __forceinline__ void load_lds16(const unsigned short* g, unsigned short* l) {
  // 16-byte global -> LDS direct copy (global_load_lds_dwordx4).
  __builtin_amdgcn_global_load_lds(
      (const __attribute__((address_space(1))) void*)g,
      (__attribute__((address_space(3))) void*)l, 16, 0, 0);
}

// ---------------- pre-pass kernels ----------------

// f32 -> bf16 elementwise (vectorized float4 -> ushort4)
__global__ void cvt_f32_bf16(const float* __restrict__ in, unsigned short* __restrict__ out, int n4) {
  int i = blockIdx.x * blockDim.x + threadIdx.x;
  int stride = gridDim.x * blockDim.x;
  for (int idx = i; idx < n4; idx += stride) {
    float4 v = ((const float4*)in)[idx];
    ushort4 o;
    o.x = f32_to_bf16(v.x); o.y = f32_to_bf16(v.y);
    o.z = f32_to_bf16(v.z); o.w = f32_to_bf16(v.w);
    ((ushort4*)out)[idx] = o;
  }
}

// f32 [R][C] row-major  ->  bf16 [C][R] row-major (transpose + cast)
__global__ void transpose_cvt(const float* __restrict__ in, unsigned short* __restrict__ out,
                              int R, int C) {
  __shared__ float tile[32][33];
  const int tx = threadIdx.x;        // 0..31
  const int ty = threadIdx.y;        // 0..7
  const int c0 = blockIdx.x * 32;
  const int r0 = blockIdx.y * 32;
  #pragma unroll
  for (int i = ty; i < 32; i += 8)
    tile[i][tx] = in[(size_t)(r0 + i) * C + c0 + tx];
  __syncthreads();
  #pragma unroll
  for (int i = ty; i < 32; i += 8)
    out[(size_t)(c0 + i) * R + r0 + tx] = f32_to_bf16(tile[tx][i]);
}

// ---------------- GEMM: C = epilogue(A @ Bt^T + bias) ----------------
// A  [M][K] bf16 row-major, Bt [N][K] bf16 row-major (i.e. B^T)
// EPI 0: relu -> bf16 out;  EPI 1: sigmoid -> f32 out
template <int EPI>
__global__ __launch_bounds__(256, 2)
void gemm_bt(const unsigned short* __restrict__ A, const unsigned short* __restrict__ Bt,
             const float* __restrict__ bias, void* __restrict__ C,
             int M, int N, int K) {
  __shared__ unsigned short lA[128 * 64];  // [row 0..127][k 0..63]
  __shared__ unsigned short lB[128 * 64];  // [col 0..127][k 0..63]

  const int tid  = threadIdx.x;
  const int lane = tid & 63;
  const int wave = tid >> 6;
  const int wr = wave >> 1;       // wave row (0/1) -> 64-row strip
  const int wc = wave & 1;        // wave col (0/1) -> 64-col strip

  const int nbx  = N >> 7;
  const int brow = blockIdx.x / nbx;
  const int bcol = blockIdx.x % nbx;

  f32x4 acc[4][4] = {};

  // staging map: flat elem = call*2048 + tid*8 over a [128][64] tile
  const int ar   = tid >> 3;            // 0..31 (row within 32-row chunk)
  const int acol = (tid & 7) * 8;       // 0,8,..,56
  const unsigned short* Ag = A  + (size_t)(brow * 128 + ar) * K + acol;
  const unsigned short* Bg = Bt + (size_t)(bcol * 128 + ar) * K + acol;
  unsigned short* lAp = lA + tid * 8;
  unsigned short* lBp = lB + tid * 8;

  // fragment read map (16x16x32: A row = lane&15, k = (lane>>4)*8 + j)
  const int fr = lane & 15;
  const int fk = (lane >> 4) * 8;

  for (int kt = 0; kt < K; kt += 64) {
    __syncthreads();
    #pragma unroll
    for (int c = 0; c < 4; ++c) {
      load_lds16(Ag + (size_t)(c * 32) * K + kt, lAp + c * 2048);
      load_lds16(Bg + (size_t)(c * 32) * K + kt, lBp + c * 2048);
    }
    __syncthreads();   // drains vmcnt -> tile visible
    #pragma unroll
    for (int kk = 0; kk < 2; ++kk) {
      bf16x8 af[4], bf[4];
      #pragma unroll
      for (int m = 0; m < 4; ++m)
        af[m] = *(const bf16x8*)&lA[(wr * 64 + m * 16 + fr) * 64 + kk * 32 + fk];
      #pragma unroll
      for (int n = 0; n < 4; ++n)
        bf[n] = *(const bf16x8*)&lB[(wc * 64 + n * 16 + fr) * 64 + kk * 32 + fk];
      #pragma unroll
      for (int m = 0; m < 4; ++m)
        #pragma unroll
        for (int n = 0; n < 4; ++n)
          acc[m][n] = __builtin_amdgcn_mfma_f32_16x16x32_bf16(af[m], bf[n], acc[m][n], 0, 0, 0);
    }
  }

  // Epilogue. C/D layout: col = lane&15, row = (lane>>4)*4 + reg
  const int crow0 = brow * 128 + wr * 64 + (lane >> 4) * 4;
  const int ccol0 = bcol * 128 + wc * 64 + (lane & 15);
  #pragma unroll
  for (int n = 0; n < 4; ++n) {
    const int col = ccol0 + n * 16;
    const float bv = bias[col];
    #pragma unroll
    for (int m = 0; m < 4; ++m) {
      #pragma unroll
      for (int i = 0; i < 4; ++i) {
        const size_t idx = (size_t)(crow0 + m * 16 + i) * N + col;
        float v = acc[m][n][i] + bv;
        if (EPI == 0) {
          v = v > 0.f ? v : 0.f;
          ((unsigned short*)C)[idx] = f32_to_bf16(v);
        } else {
          ((float*)C)[idx] = 1.f / (1.f + __expf(-v));
        }
      }
    }
  }
}

// ---------------- launch ----------------

extern "C" void kernel_launch(void* const* d_in, const int* in_sizes, int n_in,
                              void* d_out, int out_size, void* d_ws, size_t ws_size,
                              hipStream_t stream) {
  const float* x  = (const float*)d_in[0];
  const float* W1 = (const float*)d_in[1];
  const float* b1 = (const float*)d_in[2];
  const float* W2 = (const float*)d_in[3];
  const float* b2 = (const float*)d_in[4];
  float* out = (float*)d_out;

  char* ws = (char*)d_ws;
  const size_t MB = 1024 * 1024;
  unsigned short* x_bf = (unsigned short*)(ws);                 // 16 MB
  unsigned short* W1t  = (unsigned short*)(ws + 16 * MB);       // 32 MB  [HID][IN]
  unsigned short* W2t  = (unsigned short*)(ws + 48 * MB);       // 32 MB  [OUT][HID]
  unsigned short* h_bf = (unsigned short*)(ws + 80 * MB);       // 64 MB  [BATCH][HID]
  // total 144 MB of ws

  cvt_f32_bf16<<<2048, 256, 0, stream>>>(x, x_bf, (BATCH * IN_F) / 4);
  transpose_cvt<<<dim3(HID_F / 32, IN_F / 32), dim3(32, 8), 0, stream>>>(W1, W1t, IN_F, HID_F);
  transpose_cvt<<<dim3(OUT_F / 32, HID_F / 32), dim3(32, 8), 0, stream>>>(W2, W2t, HID_F, OUT_F);

  gemm_bt<0><<<(BATCH / 128) * (HID_F / 128), 256, 0, stream>>>(
      x_bf, W1t, b1, h_bf, BATCH, HID_F, IN_F);
  gemm_bt<1><<<(BATCH / 128) * (OUT_F / 128), 256, 0, stream>>>(
      h_bf, W2t, b2, out, BATCH, OUT_F, HID_F);
}

// Round 2
// 511.022 us; speedup vs baseline: 1.0215x; 1.0215x over previous
//
#include <hip/hip_runtime.h>
#include <hip/hip_bf16.h>
#include <stdint.h>

#define IN_F  2048
#define HID_F 8192
#define OUT_F 2048
#define BATCH 4096

typedef __attribute__((ext_vector_type(8))) short bf16x8;
typedef __attribute__((ext_vector_type(4))) float f32x4;
typedef __attribute__((ext_vector_type(8))) unsigned short u16x8;

__device__ __forceinline__ unsigned short f32_to_bf16(float f) {
  union { float f; uint32_t u; } v; v.f = f;
  uint32_t u = v.u;
  uint32_t r = u + 0x7FFF + ((u >> 16) & 1);   // RNE
  return (unsigned short)(r >> 16);
}

__device__ __forceinline__ void stage16(const unsigned short* g, unsigned short* l) {
  __builtin_amdgcn_global_load_lds(
      (const __attribute__((address_space(1))) void*)g,
      (__attribute__((address_space(3))) void*)l, 16, 0, 0);
}

// ---------------- pre-pass kernels ----------------

__global__ void cvt_f32_bf16(const float* __restrict__ in, unsigned short* __restrict__ out, int n4) {
  int i = blockIdx.x * blockDim.x + threadIdx.x;
  int stride = gridDim.x * blockDim.x;
  for (int idx = i; idx < n4; idx += stride) {
    float4 v = ((const float4*)in)[idx];
    ushort4 o;
    o.x = f32_to_bf16(v.x); o.y = f32_to_bf16(v.y);
    o.z = f32_to_bf16(v.z); o.w = f32_to_bf16(v.w);
    ((ushort4*)out)[idx] = o;
  }
}

// f32 [R][C] -> bf16 [C][R].  64x64 tiles, float4 loads, ushort8 stores.
__global__ void transpose_cvt(const float* __restrict__ in, unsigned short* __restrict__ out,
                              int R, int C) {
  __shared__ unsigned short t[64][72];           // t[c][r], padded stride
  const int tid = threadIdx.x;                   // 256 threads
  const int r0 = blockIdx.y * 64;
  const int c0 = blockIdx.x * 64;
  #pragma unroll
  for (int p = 0; p < 4; ++p) {
    int f4  = p * 256 + tid;                     // 0..1023
    int row = f4 >> 4;                           // 0..63
    int c   = (f4 & 15) * 4;
    float4 v = *(const float4*)&in[(size_t)(r0 + row) * C + c0 + c];
    t[c + 0][row] = f32_to_bf16(v.x);
    t[c + 1][row] = f32_to_bf16(v.y);
    t[c + 2][row] = f32_to_bf16(v.z);
    t[c + 3][row] = f32_to_bf16(v.w);
  }
  __syncthreads();
  #pragma unroll
  for (int p = 0; p < 2; ++p) {
    int u  = p * 256 + tid;                      // 0..511
    int cc = u >> 3;
    int rr = (u & 7) * 8;
    *(u16x8*)&out[(size_t)(c0 + cc) * R + r0 + rr] = *(const u16x8*)&t[cc][rr];
  }
}

// ---------------- GEMM: C = epilogue(A @ Bt^T + bias) ----------------
// A [M][K] bf16, Bt [N][K] bf16 (pre-transposed).  BM=128, BN=256, BK=64.
// 8 waves (2M x 4N), triple-buffered K-tiles, counted vmcnt, T2 swizzle.
// EPI 0: relu -> bf16 out;  EPI 1: sigmoid -> f32 out
template <int EPI>
__global__ __launch_bounds__(512, 2)
void gemm_bt(const unsigned short* __restrict__ A, const unsigned short* __restrict__ Bt,
             const float* __restrict__ bias, void* __restrict__ C,
             int M, int N, int K) {
  __shared__ unsigned short lA[3][128 * 64];     // 3 x 16 KiB
  __shared__ unsigned short lB[3][256 * 64];     // 3 x 32 KiB   (total 144 KiB)

  const int tid  = threadIdx.x;
  const int lane = tid & 63;
  const int wave = tid >> 6;
  const int wr = wave >> 2;        // 0..1 -> 64-row strip
  const int wc = wave & 3;         // 0..3 -> 64-col strip

  // T1: XCD-aware block swizzle (grid % 8 == 0 for both GEMMs)
  const int nbx = N >> 8;
  const int nwg = (M >> 7) * nbx;
  int wg = blockIdx.x;
  wg = (wg & 7) * (nwg >> 3) + (wg >> 3);
  const int brow = wg / nbx;
  const int bcol = wg % nbx;

  // ---- staging maps (pre-swizzled global source, linear LDS dest) ----
  const int srow = tid >> 3;           // 0..63
  const int w8   = (tid & 7) * 8;      // elem within row
  const unsigned short* gA[2];
  const unsigned short* gB[4];
  #pragma unroll
  for (int c = 0; c < 2; ++c) {
    int row = c * 64 + srow;
    gA[c] = A + (size_t)(brow * 128 + row) * K + (w8 ^ ((row & 7) << 3));
  }
  #pragma unroll
  for (int c = 0; c < 4; ++c) {
    int row = c * 64 + srow;
    gB[c] = Bt + (size_t)(bcol * 256 + row) * K + (w8 ^ ((row & 7) << 3));
  }
  const int ldst = tid * 8;            // lds elem offset within chunk

  const int ktiles = K >> 6;

  // prologue: stage tiles 0 and 1 (12 loads), confirm tile 0 (vmcnt 6)
  #pragma unroll
  for (int c = 0; c < 2; ++c) stage16(gA[c],      &lA[0][c * 4096 + ldst]);
  #pragma unroll
  for (int c = 0; c < 4; ++c) stage16(gB[c],      &lB[0][c * 4096 + ldst]);
  #pragma unroll
  for (int c = 0; c < 2; ++c) stage16(gA[c] + 64, &lA[1][c * 4096 + ldst]);
  #pragma unroll
  for (int c = 0; c < 4; ++c) stage16(gB[c] + 64, &lB[1][c * 4096 + ldst]);
  #pragma unroll
  for (int c = 0; c < 2; ++c) gA[c] += 128;
  #pragma unroll
  for (int c = 0; c < 4; ++c) gB[c] += 128;

  asm volatile("s_waitcnt vmcnt(6)" ::: "memory");
  __builtin_amdgcn_s_barrier();

  f32x4 acc[4][4] = {};
  const int fr = lane & 15;
  const int fk = (lane >> 4) * 8;

  int slot = 0;
  for (int jt = 0; jt < ktiles; ++jt) {
    const int nslot = (slot + 2 >= 3) ? slot - 1 : slot + 2;
    const bool pf = (jt + 2 < ktiles);

    #pragma unroll
    for (int kk = 0; kk < 2; ++kk) {
      // phase: 8 ds_read_b128 (swizzled) + 3 staged loads + 16 MFMA
      bf16x8 af[4], bf[4];
      #pragma unroll
      for (int m = 0; m < 4; ++m) {
        int row = wr * 64 + m * 16 + fr;
        af[m] = *(const bf16x8*)&lA[slot][row * 64 + ((kk * 32 + fk) ^ ((row & 7) << 3))];
      }
      #pragma unroll
      for (int n = 0; n < 4; ++n) {
        int row = wc * 64 + n * 16 + fr;
        bf[n] = *(const bf16x8*)&lB[slot][row * 64 + ((kk * 32 + fk) ^ ((row & 7) << 3))];
      }
      if (pf) {
        if (kk == 0) {
          stage16(gA[0], &lA[nslot][0 * 4096 + ldst]);
          stage16(gA[1], &lA[nslot][1 * 4096 + ldst]);
          stage16(gB[0], &lB[nslot][0 * 4096 + ldst]);
        } else {
          stage16(gB[1], &lB[nslot][1 * 4096 + ldst]);
          stage16(gB[2], &lB[nslot][2 * 4096 + ldst]);
          stage16(gB[3], &lB[nslot][3 * 4096 + ldst]);
        }
      }
      __builtin_amdgcn_s_barrier();
      asm volatile("s_waitcnt lgkmcnt(0)" ::: "memory");
      __builtin_amdgcn_s_setprio(1);
      #pragma unroll
      for (int m = 0; m < 4; ++m)
        #pragma unroll
        for (int n = 0; n < 4; ++n)
          acc[m][n] = __builtin_amdgcn_mfma_f32_16x16x32_bf16(af[m], bf[n], acc[m][n], 0, 0, 0);
      __builtin_amdgcn_s_setprio(0);
      __builtin_amdgcn_s_barrier();
    }

    if (pf) {
      #pragma unroll
      for (int c = 0; c < 2; ++c) gA[c] += 64;
      #pragma unroll
      for (int c = 0; c < 4; ++c) gB[c] += 64;
    }
    // K-tile boundary: confirm tile jt+1 landed; keep tile jt+2's 6 loads in flight
    if (jt + 1 < ktiles) {
      if (pf) asm volatile("s_waitcnt vmcnt(6)" ::: "memory");
      else    asm volatile("s_waitcnt vmcnt(0)" ::: "memory");
      __builtin_amdgcn_s_barrier();
    }
    slot = (slot + 1 >= 3) ? 0 : slot + 1;
  }

  // ---- epilogue.  C/D: col = lane&15, row = (lane>>4)*4 + i ----
  const int crow0 = brow * 128 + wr * 64 + (lane >> 4) * 4;
  const int ccol0 = bcol * 256 + wc * 64 + fr;
  #pragma unroll
  for (int n = 0; n < 4; ++n) {
    const int col = ccol0 + n * 16;
    const float bv = bias[col];
    #pragma unroll
    for (int m = 0; m < 4; ++m) {
      #pragma unroll
      for (int i = 0; i < 4; ++i) {
        const size_t idx = (size_t)(crow0 + m * 16 + i) * N + col;
        float v = acc[m][n][i] + bv;
        if (EPI == 0) {
          v = v > 0.f ? v : 0.f;
          ((unsigned short*)C)[idx] = f32_to_bf16(v);
        } else {
          ((float*)C)[idx] = 1.f / (1.f + __expf(-v));
        }
      }
    }
  }
}

// ---------------- launch ----------------

extern "C" void kernel_launch(void* const* d_in, const int* in_sizes, int n_in,
                              void* d_out, int out_size, void* d_ws, size_t ws_size,
                              hipStream_t stream) {
  const float* x  = (const float*)d_in[0];
  const float* W1 = (const float*)d_in[1];
  const float* b1 = (const float*)d_in[2];
  const float* W2 = (const float*)d_in[3];
  const float* b2 = (const float*)d_in[4];
  float* out = (float*)d_out;

  char* ws = (char*)d_ws;
  const size_t MB = 1024 * 1024;
  unsigned short* x_bf = (unsigned short*)(ws);                 // 16 MB
  unsigned short* W1t  = (unsigned short*)(ws + 16 * MB);       // 32 MB  [HID][IN]
  unsigned short* W2t  = (unsigned short*)(ws + 48 * MB);       // 32 MB  [OUT][HID]
  unsigned short* h_bf = (unsigned short*)(ws + 80 * MB);       // 64 MB  [BATCH][HID]

  cvt_f32_bf16<<<2048, 256, 0, stream>>>(x, x_bf, (BATCH * IN_F) / 4);
  transpose_cvt<<<dim3(HID_F / 64, IN_F / 64), 256, 0, stream>>>(W1, W1t, IN_F, HID_F);
  transpose_cvt<<<dim3(OUT_F / 64, HID_F / 64), 256, 0, stream>>>(W2, W2t, HID_F, OUT_F);

  gemm_bt<0><<<(BATCH / 128) * (HID_F / 256), 512, 0, stream>>>(
      x_bf, W1t, b1, h_bf, BATCH, HID_F, IN_F);
  gemm_bt<1><<<(BATCH / 128) * (OUT_F / 256), 512, 0, stream>>>(
      h_bf, W2t, b2, out, BATCH, OUT_F, HID_F);
}